// Round 6
// baseline (913.951 us; speedup 1.0000x reference)
//
#include <hip/hip_runtime.h>
#include <hip/hip_fp16.h>

constexpr int C = 128;
constexpr int N = 4096;
constexpr int B = 4;

typedef _Float16 f16x8 __attribute__((ext_vector_type(8)));
typedef _Float16 f16x4 __attribute__((ext_vector_type(4)));
typedef _Float16 f16x2 __attribute__((ext_vector_type(2)));
typedef float    f32x4 __attribute__((ext_vector_type(4)));

// ---------------------------------------------------------------------------
// Small GEMM: Y[b,o,n] = sum_c W[o,c] * X[b,c,n] (+bias[o]); O=128 fixed.
// grid (N/64, 2, B), block 256. fp32 compute; optional fp16 output.
// R5: STAT variant fuses BN sum/sumsq accumulation (atomicAdd to bnacc[2C]).
// ---------------------------------------------------------------------------
template<bool BIAS, bool HALFOUT, bool STAT>
__global__ __launch_bounds__(256) void k_gw(const float* __restrict__ W,
                                            const float* __restrict__ X,
                                            const float* __restrict__ bias,
                                            void* __restrict__ Yv,
                                            float* __restrict__ bnacc) {
  __shared__ float xs[128 * 64];
  __shared__ float wsh[128 * 65];
  const int tid = threadIdx.x;
  const int n0 = blockIdx.x * 64, o0 = blockIdx.y * 64, b = blockIdx.z;
  const float* Xb = X + (size_t)(b * C) * N + n0;
#pragma unroll
  for (int i = 0; i < 8; i++) {
    int idx = tid + i * 256;
    int c = idx >> 4, q = idx & 15;
    *(float4*)&xs[c * 64 + q * 4] = *(const float4*)&Xb[(size_t)c * N + q * 4];
  }
#pragma unroll
  for (int i = 0; i < 32; i++) {
    int idx = tid + i * 256;
    int c = idx & 127, o = idx >> 7;
    wsh[c * 65 + o] = W[(o0 + o) * C + c];
  }
  __syncthreads();
  const int to = tid >> 4, tn = tid & 15;
  float acc[4][4];
#pragma unroll
  for (int i = 0; i < 4; i++)
#pragma unroll
    for (int j = 0; j < 4; j++) acc[i][j] = 0.f;
#pragma unroll 4
  for (int c = 0; c < 128; c++) {
    const float4 x4 = *(const float4*)&xs[c * 64 + tn * 4];
    const float* wp = &wsh[c * 65 + to * 4];
    const float w0 = wp[0], w1 = wp[1], w2 = wp[2], w3 = wp[3];
    acc[0][0] += w0 * x4.x; acc[0][1] += w0 * x4.y; acc[0][2] += w0 * x4.z; acc[0][3] += w0 * x4.w;
    acc[1][0] += w1 * x4.x; acc[1][1] += w1 * x4.y; acc[1][2] += w1 * x4.z; acc[1][3] += w1 * x4.w;
    acc[2][0] += w2 * x4.x; acc[2][1] += w2 * x4.y; acc[2][2] += w2 * x4.z; acc[2][3] += w2 * x4.w;
    acc[3][0] += w3 * x4.x; acc[3][1] += w3 * x4.y; acc[3][2] += w3 * x4.z; acc[3][3] += w3 * x4.w;
  }
  const int ob = o0 + to * 4, nb = n0 + tn * 4;
#pragma unroll
  for (int i = 0; i < 4; i++) {
    const float bv_ = BIAS ? bias[ob + i] : 0.f;
    const float r0 = acc[i][0] + bv_, r1 = acc[i][1] + bv_, r2 = acc[i][2] + bv_, r3 = acc[i][3] + bv_;
    const size_t gi = (size_t)(b * C + ob + i) * N + nb;
    if (HALFOUT) {
      f16x4 h = {(_Float16)r0, (_Float16)r1, (_Float16)r2, (_Float16)r3};
      *(f16x4*)((_Float16*)Yv + gi) = h;
    } else {
      float4 r; r.x = r0; r.y = r1; r.z = r2; r.w = r3;
      *(float4*)((float*)Yv + gi) = r;
    }
    if (STAT) {
      float s = r0 + r1 + r2 + r3;
      float q = r0 * r0 + r1 * r1 + r2 * r2 + r3 * r3;
      s += __shfl_xor(s, 1, 64); q += __shfl_xor(q, 1, 64);
      s += __shfl_xor(s, 2, 64); q += __shfl_xor(q, 2, 64);
      s += __shfl_xor(s, 4, 64); q += __shfl_xor(q, 4, 64);
      s += __shfl_xor(s, 8, 64); q += __shfl_xor(q, 8, 64);
      if (tn == 0) {
        atomicAdd(&bnacc[2 * (ob + i)], s);
        atomicAdd(&bnacc[2 * (ob + i) + 1], q);
      }
    }
  }
}

// ---------------------------------------------------------------------------
// QK projection with TRANSPOSED fp16 output: QT[b][n][o] (o<32).
// grid (N/64, 1, B), block 256.
// ---------------------------------------------------------------------------
__global__ __launch_bounds__(256) void k_qkt(const float* __restrict__ W,
                                             const float* __restrict__ X,
                                             _Float16* __restrict__ QT) {
  __shared__ float xs[128 * 64];
  __shared__ float wsh[128 * 33];
  const int tid = threadIdx.x;
  const int n0 = blockIdx.x * 64, b = blockIdx.z;
  const float* Xb = X + (size_t)(b * C) * N + n0;
#pragma unroll
  for (int i = 0; i < 8; i++) {
    int idx = tid + i * 256;
    int c = idx >> 4, q = idx & 15;
    *(float4*)&xs[c * 64 + q * 4] = *(const float4*)&Xb[(size_t)c * N + q * 4];
  }
#pragma unroll
  for (int i = 0; i < 16; i++) {
    int idx = tid + i * 256;
    int c = idx & 127, o = idx >> 7;   // o in [0,32)
    wsh[c * 33 + o] = W[o * C + c];
  }
  __syncthreads();
  const int to = tid >> 4, tn = tid & 15;
  float acc[2][4];
#pragma unroll
  for (int i = 0; i < 2; i++)
#pragma unroll
    for (int j = 0; j < 4; j++) acc[i][j] = 0.f;
#pragma unroll 4
  for (int c = 0; c < 128; c++) {
    const float4 x4 = *(const float4*)&xs[c * 64 + tn * 4];
    const float w0 = wsh[c * 33 + to * 2], w1 = wsh[c * 33 + to * 2 + 1];
    acc[0][0] += w0 * x4.x; acc[0][1] += w0 * x4.y; acc[0][2] += w0 * x4.z; acc[0][3] += w0 * x4.w;
    acc[1][0] += w1 * x4.x; acc[1][1] += w1 * x4.y; acc[1][2] += w1 * x4.z; acc[1][3] += w1 * x4.w;
  }
  _Float16* Qb = QT + ((size_t)b * N + n0) * 32;
#pragma unroll
  for (int j = 0; j < 4; j++) {
    f16x2 h = {(_Float16)acc[0][j], (_Float16)acc[1][j]};
    *(f16x2*)&Qb[(tn * 4 + j) * 32 + to * 2] = h;
  }
}

// ---------------------------------------------------------------------------
// Flash-style row-stats WITHOUT materializing E (two-pass Gram sweep).
// grid (N/64, B), block 512.
// ---------------------------------------------------------------------------
__global__ __launch_bounds__(512) void k_sm(const _Float16* __restrict__ QT,
                                            const int* __restrict__ mask,
                                            float* __restrict__ rowmax,
                                            float* __restrict__ rowsi) {
  __shared__ float mb[N];          // 0 (valid m) or -1e30 (invalid m)
  __shared__ float red[2][64];
  __shared__ float rmS[64];
  const int tid = threadIdx.x;
  const int n0 = blockIdx.x * 64, b = blockIdx.y;
  const _Float16* Qb = QT + (size_t)b * N * 32;
  const int* Mb = mask + b * N;
#pragma unroll
  for (int i = 0; i < 8; i++) {
    const int v = tid + i * 512;
    mb[v] = (Mb[v] != 0) ? 0.0f : -1e30f;
  }
  const int w = tid >> 6, lane = tid & 63, quad = lane >> 4, lr = lane & 15;
  const int nw = (w & 3) * 16, mh = (w >> 2) * 64;
  const f16x8 aF = *(const f16x8*)&Qb[(size_t)(n0 + nw + lr) * 32 + quad * 8];
  __syncthreads();
  float mx[4] = {-3e38f, -3e38f, -3e38f, -3e38f};
  for (int ms = 0; ms < N; ms += 128) {
#pragma unroll
    for (int t = 0; t < 4; t++) {
      const int mrow = ms + mh + t * 16 + lr;
      const f16x8 bF = *(const f16x8*)&Qb[(size_t)mrow * 32 + quad * 8];
      f32x4 d = (f32x4){0.f, 0.f, 0.f, 0.f};
      d = __builtin_amdgcn_mfma_f32_16x16x32_f16(aF, bF, d, 0, 0, 0);
      const float bias = mb[mrow];
#pragma unroll
      for (int r = 0; r < 4; r++) mx[r] = fmaxf(mx[r], d[r] + bias);
    }
  }
#pragma unroll
  for (int r = 0; r < 4; r++) {
    float v = mx[r];
    v = fmaxf(v, __shfl_xor(v, 1, 64));
    v = fmaxf(v, __shfl_xor(v, 2, 64));
    v = fmaxf(v, __shfl_xor(v, 4, 64));
    v = fmaxf(v, __shfl_xor(v, 8, 64));
    mx[r] = v;
  }
  if (lr == 0)
#pragma unroll
    for (int r = 0; r < 4; r++) red[w >> 2][nw + quad * 4 + r] = mx[r];
  __syncthreads();
  if (tid < 64) rmS[tid] = fmaxf(red[0][tid], red[1][tid]);
  __syncthreads();
  float rmr[4];
#pragma unroll
  for (int r = 0; r < 4; r++) rmr[r] = rmS[nw + quad * 4 + r];
  float s[4] = {0.f, 0.f, 0.f, 0.f};
  for (int ms = 0; ms < N; ms += 128) {
#pragma unroll
    for (int t = 0; t < 4; t++) {
      const int mrow = ms + mh + t * 16 + lr;
      const f16x8 bF = *(const f16x8*)&Qb[(size_t)mrow * 32 + quad * 8];
      f32x4 d = (f32x4){0.f, 0.f, 0.f, 0.f};
      d = __builtin_amdgcn_mfma_f32_16x16x32_f16(aF, bF, d, 0, 0, 0);
      const float bias = mb[mrow];
#pragma unroll
      for (int r = 0; r < 4; r++) s[r] += __expf(d[r] + bias - rmr[r]);
    }
  }
#pragma unroll
  for (int r = 0; r < 4; r++) {
    float v = s[r];
    v += __shfl_xor(v, 1, 64);
    v += __shfl_xor(v, 2, 64);
    v += __shfl_xor(v, 4, 64);
    v += __shfl_xor(v, 8, 64);
    s[r] = v;
  }
  __syncthreads();
  if (lr == 0)
#pragma unroll
    for (int r = 0; r < 4; r++) red[w >> 2][nw + quad * 4 + r] = s[r];
  __syncthreads();
  if (tid < 64) {
    const int row = n0 + tid;
    const float tot = red[0][tid] + red[1][tid];
    const bool valid = (Mb[row] != 0);
    rowmax[b * N + row] = valid ? rmS[tid] : 1e30f;
    rowsi[b * N + row] = valid ? (1.0f / tot) : 0.0f;
  }
}

// ---------------------------------------------------------------------------
// Fused Gram->exp->PV, R5: software-pipelined with double-buffered LDS.
// One barrier per 64-n step; produce(k+1) overlaps consume(k).
// grid (N/32, B), block 512.
// ---------------------------------------------------------------------------
__global__ __launch_bounds__(512, 4) void k_pv(const _Float16* __restrict__ QT,
                                               const _Float16* __restrict__ XV,
                                               const float* __restrict__ H,
                                               const int* __restrict__ mask,
                                               const float* __restrict__ rowmax,
                                               const float* __restrict__ rowsi,
                                               float* __restrict__ Td) {
  __shared__ _Float16 XVs[2][128 * 72];
  __shared__ _Float16 Ps[2][32 * 72];
  __shared__ float colPart[4][32];
  __shared__ float colS[32];
  const int tid = threadIdx.x;
  const int m0 = blockIdx.x * 32, b = blockIdx.y;
  const _Float16* Qb = QT + (size_t)b * N * 32;
  const _Float16* XVb = XV + (size_t)(b * C) * N;
  const float* rmB = rowmax + b * N;
  const float* riB = rowsi + b * N;
  const int w = tid >> 6, lane = tid & 63, quad = lane >> 4, lr = lane & 15;
  const int msub = w & 1, nsub = w >> 1;
  const f16x8 aG = *(const f16x8*)&Qb[(size_t)(m0 + msub * 16 + lr) * 32 + quad * 8];
  float vmb[4];
#pragma unroll
  for (int r = 0; r < 4; r++)
    vmb[r] = (mask[b * N + m0 + msub * 16 + quad * 4 + r] != 0) ? 0.0f : -1e30f;
  const int sc0 = tid >> 3, sh0 = tid & 7;   // XV staging rows (2 vec/thread)
  const int sc1 = sc0 + 64;
  f32x4 acc[2];
  acc[0] = (f32x4){0.f, 0.f, 0.f, 0.f};
  acc[1] = (f32x4){0.f, 0.f, 0.f, 0.f};
  float cs[4] = {0.f, 0.f, 0.f, 0.f};

  auto produce = [&](int k0, int bf) {
    const int nn = k0 + nsub * 16 + lr;
    const f16x8 bG = *(const f16x8*)&Qb[(size_t)nn * 32 + quad * 8];
    const f16x8 xv0 = *(const f16x8*)&XVb[(size_t)sc0 * N + k0 + sh0 * 8];
    const f16x8 xv1 = *(const f16x8*)&XVb[(size_t)sc1 * N + k0 + sh0 * 8];
    const float rmv = rmB[nn], riv = riB[nn];
    f32x4 e = (f32x4){0.f, 0.f, 0.f, 0.f};
    e = __builtin_amdgcn_mfma_f32_16x16x32_f16(aG, bG, e, 0, 0, 0);
    *(f16x8*)&XVs[bf][sc0 * 72 + sh0 * 8] = xv0;
    *(f16x8*)&XVs[bf][sc1 * 72 + sh0 * 8] = xv1;
#pragma unroll
    for (int r = 0; r < 4; r++) {
      float p = __expf(e[r] - rmv + vmb[r]) * riv;
      p = (riv == 0.0f) ? 0.000244140625f : p;      // fully-masked row n
      cs[r] += p;
      Ps[bf][(msub * 16 + quad * 4 + r) * 72 + nsub * 16 + lr] = (_Float16)p;
    }
  };
  auto consume = [&](int bf) {
    const int c0 = w * 16;
    const f16x8 a0 = *(const f16x8*)&XVs[bf][(c0 + lr) * 72 + quad * 8];
    const f16x8 a1 = *(const f16x8*)&XVs[bf][(c0 + lr) * 72 + 32 + quad * 8];
    const f16x8 b00 = *(const f16x8*)&Ps[bf][lr * 72 + quad * 8];
    const f16x8 b01 = *(const f16x8*)&Ps[bf][lr * 72 + 32 + quad * 8];
    const f16x8 b10 = *(const f16x8*)&Ps[bf][(16 + lr) * 72 + quad * 8];
    const f16x8 b11 = *(const f16x8*)&Ps[bf][(16 + lr) * 72 + 32 + quad * 8];
    acc[0] = __builtin_amdgcn_mfma_f32_16x16x32_f16(a0, b00, acc[0], 0, 0, 0);
    acc[0] = __builtin_amdgcn_mfma_f32_16x16x32_f16(a1, b01, acc[0], 0, 0, 0);
    acc[1] = __builtin_amdgcn_mfma_f32_16x16x32_f16(a0, b10, acc[1], 0, 0, 0);
    acc[1] = __builtin_amdgcn_mfma_f32_16x16x32_f16(a1, b11, acc[1], 0, 0, 0);
  };

  produce(0, 0);
  __syncthreads();
  for (int it = 0; it < 64; it += 2) {
    if (it + 1 < 64) produce((it + 1) * 64, 1);
    consume(0);
    __syncthreads();
    if (it + 2 < 64) produce((it + 2) * 64, 0);
    consume(1);
    __syncthreads();
  }
#pragma unroll
  for (int r = 0; r < 4; r++) {
    float v = cs[r];
    v += __shfl_xor(v, 1, 64);
    v += __shfl_xor(v, 2, 64);
    v += __shfl_xor(v, 4, 64);
    v += __shfl_xor(v, 8, 64);
    cs[r] = v;
  }
  if (lr == 0)
#pragma unroll
    for (int r = 0; r < 4; r++) colPart[nsub][msub * 16 + quad * 4 + r] = cs[r];
  __syncthreads();
  if (tid < 32)
    colS[tid] = colPart[0][tid] + colPart[1][tid] + colPart[2][tid] + colPart[3][tid];
  __syncthreads();
  const float rdiv0 = 1.0f / (1e-9f + colS[lr]);
  const float rdiv1 = 1.0f / (1e-9f + colS[16 + lr]);
  const int cg = b * C + w * 16 + quad * 4;
#pragma unroll
  for (int r = 0; r < 4; r++) {
    const size_t gi0 = (size_t)(cg + r) * N + m0 + lr;
    Td[gi0] = H[gi0] - acc[0][r] * rdiv0;
    const size_t gi1 = (size_t)(cg + r) * N + m0 + 16 + lr;
    Td[gi1] = H[gi1] - acc[1][r] * rdiv1;
  }
}

// ---------------------------------------------------------------------------
// Finalize BN scale/shift from fused sum/sumsq accumulators. 1 block, 128 thr.
// ---------------------------------------------------------------------------
__global__ __launch_bounds__(128) void k_bnfin(const float* __restrict__ bnacc,
                                               const float* __restrict__ gamma,
                                               const float* __restrict__ beta,
                                               float* __restrict__ ss) {
  const int c = threadIdx.x;
  const float s = bnacc[2 * c], q = bnacc[2 * c + 1];
  const float inv = 1.0f / (B * N);
  const float mean = s * inv;
  const float var = q * inv - mean * mean;   // biased, like torch BN
  const float sc = gamma[c] * rsqrtf(var + 1e-5f);
  ss[2 * c] = sc;
  ss[2 * c + 1] = beta[c] - mean * sc;
}

// ---------------------------------------------------------------------------
// Apply BN+ReLU (+residual, +write output slice). grid 2048, 256 thr, float4.
// ---------------------------------------------------------------------------
template<bool RES>
__global__ __launch_bounds__(256) void k_apply(const float* __restrict__ T2,
                                               const float* __restrict__ ss,
                                               float* __restrict__ H,
                                               float* __restrict__ Out) {
  const int i = blockIdx.x * 256 + threadIdx.x;   // float4 index
  const int f = i * 4;
  const int c = (f >> 12) & 127;
  const float sc = ss[2 * c], sh = ss[2 * c + 1];
  const float4 t = *(const float4*)&T2[f];
  float4 r;
  r.x = fmaxf(t.x * sc + sh, 0.f);
  r.y = fmaxf(t.y * sc + sh, 0.f);
  r.z = fmaxf(t.z * sc + sh, 0.f);
  r.w = fmaxf(t.w * sc + sh, 0.f);
  if (RES) {
    const float4 h = *(const float4*)&H[f];
    r.x += h.x; r.y += h.y; r.z += h.z; r.w += h.w;
    *(float4*)&H[f] = r;
    const int b = f >> 19;                // f / (C*N)
    const int rem = f & (C * N - 1);      // c*N + n
    *(float4*)&Out[(size_t)b * (4 * C * N) + rem] = r;
  } else {
    *(float4*)&H[f] = r;
  }
}

// ---------------------------------------------------------------------------
extern "C" void kernel_launch(void* const* d_in, const int* in_sizes, int n_in,
                              void* d_out, int out_size, void* d_ws, size_t ws_size,
                              hipStream_t stream) {
  const float* x    = (const float*)d_in[0];
  const int*   mask = (const int*)  d_in[1];
  const float* w1   = (const float*)d_in[2];
  const float* g1   = (const float*)d_in[3];
  const float* b1   = (const float*)d_in[4];
  const float* w2   = (const float*)d_in[5];
  const float* g2   = (const float*)d_in[6];
  const float* b2   = (const float*)d_in[7];
  const float* wqk  = (const float*)d_in[8];
  const float* wv   = (const float*)d_in[9];
  const float* bv   = (const float*)d_in[10];
  const float* wt   = (const float*)d_in[11];
  const float* bt   = (const float*)d_in[12];
  const float* sg   = (const float*)d_in[13];
  const float* sb   = (const float*)d_in[14];
  float* out = (float*)d_out;

  char* p = (char*)d_ws;
  auto alloc = [&](size_t bytes) { char* r = p; p += (bytes + 255) & ~(size_t)255; return r; };
  float*    H      = (float*)   alloc((size_t)B * C * N * 4);
  float*    T2     = (float*)   alloc((size_t)B * C * N * 4);
  float*    Td     = (float*)   alloc((size_t)B * C * N * 4);
  _Float16* XQKT   = (_Float16*)alloc((size_t)B * N * 32 * 2);
  _Float16* XV     = (_Float16*)alloc((size_t)B * C * N * 2);
  float*    rowmax = (float*)   alloc((size_t)B * N * 4);
  float*    rowsi  = (float*)   alloc((size_t)B * N * 4);
  float*    ss     = (float*)   alloc((size_t)C * 2 * 4);
  float*    bnacc  = (float*)   alloc((size_t)C * 2 * 4);
  (void)ws_size;

  // ---- stem: two conv1d(+BN+ReLU), BN stats fused into conv epilogue ----
  hipMemsetAsync(bnacc, 0, C * 2 * sizeof(float), stream);
  k_gw<false, false, true><<<dim3(64, 2, B), 256, 0, stream>>>(w1, x, nullptr, T2, bnacc);
  k_bnfin<<<1, 128, 0, stream>>>(bnacc, g1, b1, ss);
  k_apply<false><<<2048, 256, 0, stream>>>(T2, ss, H, nullptr);
  hipMemsetAsync(bnacc, 0, C * 2 * sizeof(float), stream);
  k_gw<false, false, true><<<dim3(64, 2, B), 256, 0, stream>>>(w2, H, nullptr, T2, bnacc);
  k_bnfin<<<1, 128, 0, stream>>>(bnacc, g2, b2, ss);
  k_apply<false><<<2048, 256, 0, stream>>>(T2, ss, H, nullptr);

  // ---- 4 chained offset-attention layers (flash-style, no E buffer) ----
  for (int L = 0; L < 4; L++) {
    k_qkt<<<dim3(64, 1, B), 256, 0, stream>>>(wqk + (size_t)L * 32 * C, H, XQKT);
    k_gw<true, true, false><<<dim3(64, 2, B), 256, 0, stream>>>(wv + (size_t)L * C * C, H, bv + L * C, XV, nullptr);
    k_sm<<<dim3(64, B), 512, 0, stream>>>(XQKT, mask, rowmax, rowsi);
    k_pv<<<dim3(128, B), 512, 0, stream>>>(XQKT, XV, H, mask, rowmax, rowsi, Td);
    hipMemsetAsync(bnacc, 0, C * 2 * sizeof(float), stream);
    k_gw<true, false, true><<<dim3(64, 2, B), 256, 0, stream>>>(wt + (size_t)L * C * C, Td, bt + L * C, T2, bnacc);
    k_bnfin<<<1, 128, 0, stream>>>(bnacc, sg + L * C, sb + L * C, ss);
    k_apply<true><<<2048, 256, 0, stream>>>(T2, ss, H, out + (size_t)L * C * N);
  }
}

// Round 7
// 618.312 us; speedup vs baseline: 1.4781x; 1.4781x over previous
//
#include <hip/hip_runtime.h>
#include <hip/hip_fp16.h>

constexpr int C = 128;
constexpr int N = 4096;
constexpr int B = 4;

typedef _Float16 f16x8 __attribute__((ext_vector_type(8)));
typedef _Float16 f16x4 __attribute__((ext_vector_type(4)));
typedef _Float16 f16x2 __attribute__((ext_vector_type(2)));
typedef float    f32x4 __attribute__((ext_vector_type(4)));

// ---------------------------------------------------------------------------
// Small GEMM: Y[b,o,n] = sum_c W[o,c] * X[b,c,n] (+bias[o]); O=128 fixed.
// grid (N/64, 2, B), block 256. fp32 compute; optional fp16 output.
// R7: STAT writes contention-free per-block BN partials (no atomics):
//   bnpart[c*512 + part] = sum, bnpart[c*512 + 256 + part] = sumsq,
//   part = blockIdx.x*4 + blockIdx.z in [0,256).
// ---------------------------------------------------------------------------
template<bool BIAS, bool HALFOUT, bool STAT>
__global__ __launch_bounds__(256) void k_gw(const float* __restrict__ W,
                                            const float* __restrict__ X,
                                            const float* __restrict__ bias,
                                            void* __restrict__ Yv,
                                            float* __restrict__ bnpart) {
  __shared__ float xs[128 * 64];
  __shared__ float wsh[128 * 65];
  const int tid = threadIdx.x;
  const int n0 = blockIdx.x * 64, o0 = blockIdx.y * 64, b = blockIdx.z;
  const float* Xb = X + (size_t)(b * C) * N + n0;
#pragma unroll
  for (int i = 0; i < 8; i++) {
    int idx = tid + i * 256;
    int c = idx >> 4, q = idx & 15;
    *(float4*)&xs[c * 64 + q * 4] = *(const float4*)&Xb[(size_t)c * N + q * 4];
  }
#pragma unroll
  for (int i = 0; i < 32; i++) {
    int idx = tid + i * 256;
    int c = idx & 127, o = idx >> 7;
    wsh[c * 65 + o] = W[(o0 + o) * C + c];
  }
  __syncthreads();
  const int to = tid >> 4, tn = tid & 15;
  float acc[4][4];
#pragma unroll
  for (int i = 0; i < 4; i++)
#pragma unroll
    for (int j = 0; j < 4; j++) acc[i][j] = 0.f;
#pragma unroll 4
  for (int c = 0; c < 128; c++) {
    const float4 x4 = *(const float4*)&xs[c * 64 + tn * 4];
    const float* wp = &wsh[c * 65 + to * 4];
    const float w0 = wp[0], w1 = wp[1], w2 = wp[2], w3 = wp[3];
    acc[0][0] += w0 * x4.x; acc[0][1] += w0 * x4.y; acc[0][2] += w0 * x4.z; acc[0][3] += w0 * x4.w;
    acc[1][0] += w1 * x4.x; acc[1][1] += w1 * x4.y; acc[1][2] += w1 * x4.z; acc[1][3] += w1 * x4.w;
    acc[2][0] += w2 * x4.x; acc[2][1] += w2 * x4.y; acc[2][2] += w2 * x4.z; acc[2][3] += w2 * x4.w;
    acc[3][0] += w3 * x4.x; acc[3][1] += w3 * x4.y; acc[3][2] += w3 * x4.z; acc[3][3] += w3 * x4.w;
  }
  const int ob = o0 + to * 4, nb = n0 + tn * 4;
  const int part = blockIdx.x * 4 + b;
#pragma unroll
  for (int i = 0; i < 4; i++) {
    const float bv_ = BIAS ? bias[ob + i] : 0.f;
    const float r0 = acc[i][0] + bv_, r1 = acc[i][1] + bv_, r2 = acc[i][2] + bv_, r3 = acc[i][3] + bv_;
    const size_t gi = (size_t)(b * C + ob + i) * N + nb;
    if (HALFOUT) {
      f16x4 h = {(_Float16)r0, (_Float16)r1, (_Float16)r2, (_Float16)r3};
      *(f16x4*)((_Float16*)Yv + gi) = h;
    } else {
      float4 r; r.x = r0; r.y = r1; r.z = r2; r.w = r3;
      *(float4*)((float*)Yv + gi) = r;
    }
    if (STAT) {
      float s = r0 + r1 + r2 + r3;
      float q = r0 * r0 + r1 * r1 + r2 * r2 + r3 * r3;
      s += __shfl_xor(s, 1, 64); q += __shfl_xor(q, 1, 64);
      s += __shfl_xor(s, 2, 64); q += __shfl_xor(q, 2, 64);
      s += __shfl_xor(s, 4, 64); q += __shfl_xor(q, 4, 64);
      s += __shfl_xor(s, 8, 64); q += __shfl_xor(q, 8, 64);
      if (tn == 0) {
        bnpart[(ob + i) * 512 + part] = s;
        bnpart[(ob + i) * 512 + 256 + part] = q;
      }
    }
  }
}

// ---------------------------------------------------------------------------
// QK projection with TRANSPOSED fp16 output: QT[b][n][o] (o<32).
// grid (N/64, 1, B), block 256.
// ---------------------------------------------------------------------------
__global__ __launch_bounds__(256) void k_qkt(const float* __restrict__ W,
                                             const float* __restrict__ X,
                                             _Float16* __restrict__ QT) {
  __shared__ float xs[128 * 64];
  __shared__ float wsh[128 * 33];
  const int tid = threadIdx.x;
  const int n0 = blockIdx.x * 64, b = blockIdx.z;
  const float* Xb = X + (size_t)(b * C) * N + n0;
#pragma unroll
  for (int i = 0; i < 8; i++) {
    int idx = tid + i * 256;
    int c = idx >> 4, q = idx & 15;
    *(float4*)&xs[c * 64 + q * 4] = *(const float4*)&Xb[(size_t)c * N + q * 4];
  }
#pragma unroll
  for (int i = 0; i < 16; i++) {
    int idx = tid + i * 256;
    int c = idx & 127, o = idx >> 7;   // o in [0,32)
    wsh[c * 33 + o] = W[o * C + c];
  }
  __syncthreads();
  const int to = tid >> 4, tn = tid & 15;
  float acc[2][4];
#pragma unroll
  for (int i = 0; i < 2; i++)
#pragma unroll
    for (int j = 0; j < 4; j++) acc[i][j] = 0.f;
#pragma unroll 4
  for (int c = 0; c < 128; c++) {
    const float4 x4 = *(const float4*)&xs[c * 64 + tn * 4];
    const float w0 = wsh[c * 33 + to * 2], w1 = wsh[c * 33 + to * 2 + 1];
    acc[0][0] += w0 * x4.x; acc[0][1] += w0 * x4.y; acc[0][2] += w0 * x4.z; acc[0][3] += w0 * x4.w;
    acc[1][0] += w1 * x4.x; acc[1][1] += w1 * x4.y; acc[1][2] += w1 * x4.z; acc[1][3] += w1 * x4.w;
  }
  _Float16* Qb = QT + ((size_t)b * N + n0) * 32;
#pragma unroll
  for (int j = 0; j < 4; j++) {
    f16x2 h = {(_Float16)acc[0][j], (_Float16)acc[1][j]};
    *(f16x2*)&Qb[(tn * 4 + j) * 32 + to * 2] = h;
  }
}

// ---------------------------------------------------------------------------
// Flash-style row-stats WITHOUT materializing E (two-pass Gram sweep).
// grid (N/64, B), block 512.
// ---------------------------------------------------------------------------
__global__ __launch_bounds__(512) void k_sm(const _Float16* __restrict__ QT,
                                            const int* __restrict__ mask,
                                            float* __restrict__ rowmax,
                                            float* __restrict__ rowsi) {
  __shared__ float mb[N];          // 0 (valid m) or -1e30 (invalid m)
  __shared__ float red[2][64];
  __shared__ float rmS[64];
  const int tid = threadIdx.x;
  const int n0 = blockIdx.x * 64, b = blockIdx.y;
  const _Float16* Qb = QT + (size_t)b * N * 32;
  const int* Mb = mask + b * N;
#pragma unroll
  for (int i = 0; i < 8; i++) {
    const int v = tid + i * 512;
    mb[v] = (Mb[v] != 0) ? 0.0f : -1e30f;
  }
  const int w = tid >> 6, lane = tid & 63, quad = lane >> 4, lr = lane & 15;
  const int nw = (w & 3) * 16, mh = (w >> 2) * 64;
  const f16x8 aF = *(const f16x8*)&Qb[(size_t)(n0 + nw + lr) * 32 + quad * 8];
  __syncthreads();
  float mx[4] = {-3e38f, -3e38f, -3e38f, -3e38f};
  for (int ms = 0; ms < N; ms += 128) {
#pragma unroll
    for (int t = 0; t < 4; t++) {
      const int mrow = ms + mh + t * 16 + lr;
      const f16x8 bF = *(const f16x8*)&Qb[(size_t)mrow * 32 + quad * 8];
      f32x4 d = (f32x4){0.f, 0.f, 0.f, 0.f};
      d = __builtin_amdgcn_mfma_f32_16x16x32_f16(aF, bF, d, 0, 0, 0);
      const float bias = mb[mrow];
#pragma unroll
      for (int r = 0; r < 4; r++) mx[r] = fmaxf(mx[r], d[r] + bias);
    }
  }
#pragma unroll
  for (int r = 0; r < 4; r++) {
    float v = mx[r];
    v = fmaxf(v, __shfl_xor(v, 1, 64));
    v = fmaxf(v, __shfl_xor(v, 2, 64));
    v = fmaxf(v, __shfl_xor(v, 4, 64));
    v = fmaxf(v, __shfl_xor(v, 8, 64));
    mx[r] = v;
  }
  if (lr == 0)
#pragma unroll
    for (int r = 0; r < 4; r++) red[w >> 2][nw + quad * 4 + r] = mx[r];
  __syncthreads();
  if (tid < 64) rmS[tid] = fmaxf(red[0][tid], red[1][tid]);
  __syncthreads();
  float rmr[4];
#pragma unroll
  for (int r = 0; r < 4; r++) rmr[r] = rmS[nw + quad * 4 + r];
  float s[4] = {0.f, 0.f, 0.f, 0.f};
  for (int ms = 0; ms < N; ms += 128) {
#pragma unroll
    for (int t = 0; t < 4; t++) {
      const int mrow = ms + mh + t * 16 + lr;
      const f16x8 bF = *(const f16x8*)&Qb[(size_t)mrow * 32 + quad * 8];
      f32x4 d = (f32x4){0.f, 0.f, 0.f, 0.f};
      d = __builtin_amdgcn_mfma_f32_16x16x32_f16(aF, bF, d, 0, 0, 0);
      const float bias = mb[mrow];
#pragma unroll
      for (int r = 0; r < 4; r++) s[r] += __expf(d[r] + bias - rmr[r]);
    }
  }
#pragma unroll
  for (int r = 0; r < 4; r++) {
    float v = s[r];
    v += __shfl_xor(v, 1, 64);
    v += __shfl_xor(v, 2, 64);
    v += __shfl_xor(v, 4, 64);
    v += __shfl_xor(v, 8, 64);
    s[r] = v;
  }
  __syncthreads();
  if (lr == 0)
#pragma unroll
    for (int r = 0; r < 4; r++) red[w >> 2][nw + quad * 4 + r] = s[r];
  __syncthreads();
  if (tid < 64) {
    const int row = n0 + tid;
    const float tot = red[0][tid] + red[1][tid];
    const bool valid = (Mb[row] != 0);
    rowmax[b * N + row] = valid ? rmS[tid] : 1e30f;
    rowsi[b * N + row] = valid ? (1.0f / tot) : 0.0f;
  }
}

// ---------------------------------------------------------------------------
// Fused Gram->exp->PV, software-pipelined with double-buffered LDS.
// One barrier per 64-n step; produce(k+1) overlaps consume(k).
// grid (N/32, B), block 512.
// ---------------------------------------------------------------------------
__global__ __launch_bounds__(512, 4) void k_pv(const _Float16* __restrict__ QT,
                                               const _Float16* __restrict__ XV,
                                               const float* __restrict__ H,
                                               const int* __restrict__ mask,
                                               const float* __restrict__ rowmax,
                                               const float* __restrict__ rowsi,
                                               float* __restrict__ Td) {
  __shared__ _Float16 XVs[2][128 * 72];
  __shared__ _Float16 Ps[2][32 * 72];
  __shared__ float colPart[4][32];
  __shared__ float colS[32];
  const int tid = threadIdx.x;
  const int m0 = blockIdx.x * 32, b = blockIdx.y;
  const _Float16* Qb = QT + (size_t)b * N * 32;
  const _Float16* XVb = XV + (size_t)(b * C) * N;
  const float* rmB = rowmax + b * N;
  const float* riB = rowsi + b * N;
  const int w = tid >> 6, lane = tid & 63, quad = lane >> 4, lr = lane & 15;
  const int msub = w & 1, nsub = w >> 1;
  const f16x8 aG = *(const f16x8*)&Qb[(size_t)(m0 + msub * 16 + lr) * 32 + quad * 8];
  float vmb[4];
#pragma unroll
  for (int r = 0; r < 4; r++)
    vmb[r] = (mask[b * N + m0 + msub * 16 + quad * 4 + r] != 0) ? 0.0f : -1e30f;
  const int sc0 = tid >> 3, sh0 = tid & 7;   // XV staging rows (2 vec/thread)
  const int sc1 = sc0 + 64;
  f32x4 acc[2];
  acc[0] = (f32x4){0.f, 0.f, 0.f, 0.f};
  acc[1] = (f32x4){0.f, 0.f, 0.f, 0.f};
  float cs[4] = {0.f, 0.f, 0.f, 0.f};

  auto produce = [&](int k0, int bf) {
    const int nn = k0 + nsub * 16 + lr;
    const f16x8 bG = *(const f16x8*)&Qb[(size_t)nn * 32 + quad * 8];
    const f16x8 xv0 = *(const f16x8*)&XVb[(size_t)sc0 * N + k0 + sh0 * 8];
    const f16x8 xv1 = *(const f16x8*)&XVb[(size_t)sc1 * N + k0 + sh0 * 8];
    const float rmv = rmB[nn], riv = riB[nn];
    f32x4 e = (f32x4){0.f, 0.f, 0.f, 0.f};
    e = __builtin_amdgcn_mfma_f32_16x16x32_f16(aG, bG, e, 0, 0, 0);
    *(f16x8*)&XVs[bf][sc0 * 72 + sh0 * 8] = xv0;
    *(f16x8*)&XVs[bf][sc1 * 72 + sh0 * 8] = xv1;
#pragma unroll
    for (int r = 0; r < 4; r++) {
      float p = __expf(e[r] - rmv + vmb[r]) * riv;
      p = (riv == 0.0f) ? 0.000244140625f : p;      // fully-masked row n
      cs[r] += p;
      Ps[bf][(msub * 16 + quad * 4 + r) * 72 + nsub * 16 + lr] = (_Float16)p;
    }
  };
  auto consume = [&](int bf) {
    const int c0 = w * 16;
    const f16x8 a0 = *(const f16x8*)&XVs[bf][(c0 + lr) * 72 + quad * 8];
    const f16x8 a1 = *(const f16x8*)&XVs[bf][(c0 + lr) * 72 + 32 + quad * 8];
    const f16x8 b00 = *(const f16x8*)&Ps[bf][lr * 72 + quad * 8];
    const f16x8 b01 = *(const f16x8*)&Ps[bf][lr * 72 + 32 + quad * 8];
    const f16x8 b10 = *(const f16x8*)&Ps[bf][(16 + lr) * 72 + quad * 8];
    const f16x8 b11 = *(const f16x8*)&Ps[bf][(16 + lr) * 72 + 32 + quad * 8];
    acc[0] = __builtin_amdgcn_mfma_f32_16x16x32_f16(a0, b00, acc[0], 0, 0, 0);
    acc[0] = __builtin_amdgcn_mfma_f32_16x16x32_f16(a1, b01, acc[0], 0, 0, 0);
    acc[1] = __builtin_amdgcn_mfma_f32_16x16x32_f16(a0, b10, acc[1], 0, 0, 0);
    acc[1] = __builtin_amdgcn_mfma_f32_16x16x32_f16(a1, b11, acc[1], 0, 0, 0);
  };

  produce(0, 0);
  __syncthreads();
  for (int it = 0; it < 64; it += 2) {
    if (it + 1 < 64) produce((it + 1) * 64, 1);
    consume(0);
    __syncthreads();
    if (it + 2 < 64) produce((it + 2) * 64, 0);
    consume(1);
    __syncthreads();
  }
#pragma unroll
  for (int r = 0; r < 4; r++) {
    float v = cs[r];
    v += __shfl_xor(v, 1, 64);
    v += __shfl_xor(v, 2, 64);
    v += __shfl_xor(v, 4, 64);
    v += __shfl_xor(v, 8, 64);
    cs[r] = v;
  }
  if (lr == 0)
#pragma unroll
    for (int r = 0; r < 4; r++) colPart[nsub][msub * 16 + quad * 4 + r] = cs[r];
  __syncthreads();
  if (tid < 32)
    colS[tid] = colPart[0][tid] + colPart[1][tid] + colPart[2][tid] + colPart[3][tid];
  __syncthreads();
  const float rdiv0 = 1.0f / (1e-9f + colS[lr]);
  const float rdiv1 = 1.0f / (1e-9f + colS[16 + lr]);
  const int cg = b * C + w * 16 + quad * 4;
#pragma unroll
  for (int r = 0; r < 4; r++) {
    const size_t gi0 = (size_t)(cg + r) * N + m0 + lr;
    Td[gi0] = H[gi0] - acc[0][r] * rdiv0;
    const size_t gi1 = (size_t)(cg + r) * N + m0 + 16 + lr;
    Td[gi1] = H[gi1] - acc[1][r] * rdiv1;
  }
}

// ---------------------------------------------------------------------------
// Apply BN+ReLU (+residual, +write output slice). grid 2048, 256 thr, float4.
// R7: each block covers 1024 consecutive floats -> exactly ONE channel;
// reduces that channel's 512 BN partials in-block (deletes k_bnfin + memset).
// ---------------------------------------------------------------------------
template<bool RES>
__global__ __launch_bounds__(256) void k_apply(const float* __restrict__ T2,
                                               const float* __restrict__ bnpart,
                                               const float* __restrict__ gamma,
                                               const float* __restrict__ beta,
                                               float* __restrict__ H,
                                               float* __restrict__ Out) {
  __shared__ float rs[4], rq[4], bc[2];
  const int tid = threadIdx.x;
  const int f = (blockIdx.x * 256 + tid) * 4;
  const int c = (blockIdx.x >> 2) & 127;
  // --- reduce this channel's 256 (sum, sumsq) partials ---
  float s = bnpart[c * 512 + tid];
  float q = bnpart[c * 512 + 256 + tid];
#pragma unroll
  for (int o = 1; o <= 32; o <<= 1) { s += __shfl_xor(s, o, 64); q += __shfl_xor(q, o, 64); }
  if ((tid & 63) == 0) { rs[tid >> 6] = s; rq[tid >> 6] = q; }
  __syncthreads();
  if (tid == 0) {
    const float st = rs[0] + rs[1] + rs[2] + rs[3];
    const float qt = rq[0] + rq[1] + rq[2] + rq[3];
    const float inv = 1.0f / (B * N);
    const float mean = st * inv;
    const float var = qt * inv - mean * mean;   // biased, like torch BN
    const float sc = gamma[c] * rsqrtf(var + 1e-5f);
    bc[0] = sc;
    bc[1] = beta[c] - mean * sc;
  }
  __syncthreads();
  const float sc = bc[0], sh = bc[1];
  const float4 t = *(const float4*)&T2[f];
  float4 r;
  r.x = fmaxf(t.x * sc + sh, 0.f);
  r.y = fmaxf(t.y * sc + sh, 0.f);
  r.z = fmaxf(t.z * sc + sh, 0.f);
  r.w = fmaxf(t.w * sc + sh, 0.f);
  if (RES) {
    const float4 h = *(const float4*)&H[f];
    r.x += h.x; r.y += h.y; r.z += h.z; r.w += h.w;
    *(float4*)&H[f] = r;
    const int b = f >> 19;                // f / (C*N)
    const int rem = f & (C * N - 1);      // c*N + n
    *(float4*)&Out[(size_t)b * (4 * C * N) + rem] = r;
  } else {
    *(float4*)&H[f] = r;
  }
}

// ---------------------------------------------------------------------------
extern "C" void kernel_launch(void* const* d_in, const int* in_sizes, int n_in,
                              void* d_out, int out_size, void* d_ws, size_t ws_size,
                              hipStream_t stream) {
  const float* x    = (const float*)d_in[0];
  const int*   mask = (const int*)  d_in[1];
  const float* w1   = (const float*)d_in[2];
  const float* g1   = (const float*)d_in[3];
  const float* b1   = (const float*)d_in[4];
  const float* w2   = (const float*)d_in[5];
  const float* g2   = (const float*)d_in[6];
  const float* b2   = (const float*)d_in[7];
  const float* wqk  = (const float*)d_in[8];
  const float* wv   = (const float*)d_in[9];
  const float* bv   = (const float*)d_in[10];
  const float* wt   = (const float*)d_in[11];
  const float* bt   = (const float*)d_in[12];
  const float* sg   = (const float*)d_in[13];
  const float* sb   = (const float*)d_in[14];
  float* out = (float*)d_out;

  char* p = (char*)d_ws;
  auto alloc = [&](size_t bytes) { char* r = p; p += (bytes + 255) & ~(size_t)255; return r; };
  float*    H      = (float*)   alloc((size_t)B * C * N * 4);
  float*    T2     = (float*)   alloc((size_t)B * C * N * 4);
  float*    Td     = (float*)   alloc((size_t)B * C * N * 4);
  _Float16* XQKT   = (_Float16*)alloc((size_t)B * N * 32 * 2);
  _Float16* XV     = (_Float16*)alloc((size_t)B * C * N * 2);
  float*    rowmax = (float*)   alloc((size_t)B * N * 4);
  float*    rowsi  = (float*)   alloc((size_t)B * N * 4);
  float*    bnpart = (float*)   alloc((size_t)C * 512 * 4);
  (void)ws_size;

  // ---- stem: two conv1d(+BN+ReLU), BN partials fused into conv epilogue ----
  k_gw<false, false, true><<<dim3(64, 2, B), 256, 0, stream>>>(w1, x, nullptr, T2, bnpart);
  k_apply<false><<<2048, 256, 0, stream>>>(T2, bnpart, g1, b1, H, nullptr);
  k_gw<false, false, true><<<dim3(64, 2, B), 256, 0, stream>>>(w2, H, nullptr, T2, bnpart);
  k_apply<false><<<2048, 256, 0, stream>>>(T2, bnpart, g2, b2, H, nullptr);

  // ---- 4 chained offset-attention layers (flash-style, no E buffer) ----
  for (int L = 0; L < 4; L++) {
    k_qkt<<<dim3(64, 1, B), 256, 0, stream>>>(wqk + (size_t)L * 32 * C, H, XQKT);
    k_gw<true, true, false><<<dim3(64, 2, B), 256, 0, stream>>>(wv + (size_t)L * C * C, H, bv + L * C, XV, nullptr);
    k_sm<<<dim3(64, B), 512, 0, stream>>>(XQKT, mask, rowmax, rowsi);
    k_pv<<<dim3(128, B), 512, 0, stream>>>(XQKT, XV, H, mask, rowmax, rowsi, Td);
    k_gw<true, false, true><<<dim3(64, 2, B), 256, 0, stream>>>(wt + (size_t)L * C * C, Td, bt + L * C, T2, bnpart);
    k_apply<true><<<2048, 256, 0, stream>>>(T2, bnpart, sg + L * C, sb + L * C, H, out + (size_t)L * C * N);
  }
}